// Round 6
// baseline (387.725 us; speedup 1.0000x reference)
//
#include <hip/hip_runtime.h>
#include <hip/hip_bf16.h>

#define BS 8
#define SEQ 512
#define DKDIM 2048

using bf16x8 = __attribute__((ext_vector_type(8))) __bf16;
using f32x4  = __attribute__((ext_vector_type(4))) float;

__device__ __forceinline__ unsigned short f2bf(float f) {
    unsigned int u = __builtin_bit_cast(unsigned int, f);
    u += 0x7FFFu + ((u >> 16) & 1u);
    return (unsigned short)(u >> 16);
}

__device__ __forceinline__ void gload_lds16(const unsigned short* g, unsigned short* l) {
    __builtin_amdgcn_global_load_lds(
        (const __attribute__((address_space(1))) unsigned int*)g,
        (__attribute__((address_space(3))) unsigned int*)l, 16, 0, 0);
}

#define PH_BARRIER() asm volatile("s_barrier" ::: "memory")

// ---------------------------------------------------------------------------
// Transpose+convert: in [SEQ][DK] f32 (per batch) -> out [DK][SEQ] bf16
// ---------------------------------------------------------------------------
__global__ __launch_bounds__(256) void transpose_conv_kernel(
    const float* __restrict__ q, const float* __restrict__ k,
    unsigned short* __restrict__ qT, unsigned short* __restrict__ kT)
{
    int z = blockIdx.z;
    const float* in = (z < BS) ? q : k;
    unsigned short* out = (z < BS) ? qT : kT;
    int b = z & (BS - 1);
    in  += (size_t)b * SEQ * DKDIM;
    out += (size_t)b * DKDIM * SEQ;
    int s0 = blockIdx.y * 64;
    int d0 = blockIdx.x * 64;
    __shared__ unsigned short tile[64][66];
    int t = threadIdx.x;
    int tr  = t >> 4;
    int tc4 = (t & 15) * 4;
    #pragma unroll
    for (int p = 0; p < 4; ++p) {
        int s = p * 16 + tr;
        float4 v4 = *reinterpret_cast<const float4*>(&in[(size_t)(s0 + s) * DKDIM + d0 + tc4]);
        tile[s][tc4 + 0] = f2bf(v4.x);
        tile[s][tc4 + 1] = f2bf(v4.y);
        tile[s][tc4 + 2] = f2bf(v4.z);
        tile[s][tc4 + 3] = f2bf(v4.w);
    }
    __syncthreads();
    #pragma unroll
    for (int p = 0; p < 4; ++p) {
        int d = p * 16 + tr;
        ushort4 o;
        o.x = tile[tc4 + 0][d];
        o.y = tile[tc4 + 1][d];
        o.z = tile[tc4 + 2][d];
        o.w = tile[tc4 + 3][d];
        *reinterpret_cast<ushort4*>(&out[(size_t)(d0 + d) * SEQ + s0 + tc4]) = o;
    }
}

// ---------------------------------------------------------------------------
// GEMM1: E = exp(scale*(qT kT^T)), bf16, + fused column partial sums.
// 256x256 tile, BK=32, NT=16, 8 waves (2Mx4N), wave tile 128x64.
// LDS = 2 bufs x (A 16KB + B 16KB) = 64 KB  =>  2 blocks/CU (the r5 fix:
// at 128KB/1-block the lockstep schedule had nothing to overlap with).
// 4 phases/K-tile, 8 MFMA each (quadrant = m-half x n-half, 1 K-step).
// Read-group-matched halves: A by row&64, B by row&32 (as r4, verified).
// Stage slots: ph0 A1(tt+1)->buf^1 | ph1 A0(tt+2)->buf | ph2 B0(tt+2)->buf
// | ph3 B1(tt+2)->buf.  1 gload/thread per stage call.
// Tile-end vmcnt(3): leaves {tt.ph1,ph2,ph3} (tile tt+2's A0,B0,B1) in
// flight; everything older (incl. all of tile tt+1) proven landed before
// the tile-end barrier.  vmcnt(0) at tt==NT-2.
// Swizzle (4 chunks/row): swz(r)=(r&3)^((r>>2)&3); pre-XORed source chunk,
// same XOR on ds_read (involution).  Bank check: 2-way max (free, m136).
// XCD swizzle: 1D grid 512, chunk-bijective => XCD i gets batch i; its
// qT+kT (4MB) fit the XCD's 4MB L2.
// ---------------------------------------------------------------------------
__global__ __launch_bounds__(512, 4) void gemm1_qk_exp(
    const unsigned short* __restrict__ A,   // qT [b][2048][512]
    const unsigned short* __restrict__ B,   // kT [b][2048][512]
    unsigned short* __restrict__ E,         // [b][2048][2048]
    float* __restrict__ rpart,              // [16][BS][2048]
    float scale)
{
    constexpr int K = SEQ;      // 512
    constexpr int N = DKDIM;    // 2048
    constexpr int NT = K / 32;  // 16

    int wg = blockIdx.x;                    // 0..511
    int swz = (wg & 7) * 64 + (wg >> 3);    // bijective, 512 = 8*64
    int bz = swz >> 6, rem = swz & 63, by = rem >> 3, bx = rem & 7;

    const unsigned short* Ab = A + ((size_t)bz * DKDIM + by * 256) * K;
    const unsigned short* Bb = B + ((size_t)bz * DKDIM + bx * 256) * K;

    __shared__ unsigned short lds[2][2][256 * 32];   // 64 KB

    int t = threadIdx.x;
    int w = t >> 6, l = t & 63;
    int wm = w >> 2, wn = w & 3;
    int lm = l & 15, lg = l >> 4;

    // ---- staging addressing (hoisted) ----
    // A: thread t -> panel row rrA + grpA*128 (+h*64), phys chunk pcA
    int rrA = (t & 255) >> 2, grpA = t >> 8, pcA = t & 3;
    int swA = (rrA & 3) ^ ((rrA >> 2) & 3);
    const unsigned short* pAsrc = Ab + (size_t)(rrA + grpA * 128) * K + ((pcA ^ swA) << 3);
    int dstA = (t & 255) * 8 + grpA * 4096;          // + h*2048
    // B: thread t -> panel row jB + gB*64 (+h*32), phys chunk pcB
    int jB = (t >> 2) & 31, gB = t >> 7, pcB = t & 3;
    int swB = (jB & 3) ^ ((jB >> 2) & 3);
    const unsigned short* pBsrc = Bb + (size_t)(jB + gB * 64) * K + ((pcB ^ swB) << 3);
    int dstB = (t & 127) * 8 + gB * 2048;            // + h*1024

    // ---- ds_read byte offsets (hoisted) ----
    int swl = (lm & 3) ^ ((lm >> 2) & 3);
    int pch = ((lg ^ swl) << 3);                     // element offset within row
    int aoff[2][4], boff[4];
    #pragma unroll
    for (int h = 0; h < 2; ++h)
        #pragma unroll
        for (int mf = 0; mf < 4; ++mf) {
            int arow = wm * 128 + h * 64 + mf * 16 + lm;
            aoff[h][mf] = (arow * 32 + pch) * 2;
        }
    #pragma unroll
    for (int nf = 0; nf < 4; ++nf) {
        int brow = wn * 64 + nf * 16 + lm;
        boff[nf] = (brow * 32 + pch) * 2;
    }

#define LD_A(buf, h, mf) \
    (*reinterpret_cast<const bf16x8*>((const char*)(&lds[buf][0][0]) + aoff[h][mf]))
#define LD_B(buf, nf) \
    (*reinterpret_cast<const bf16x8*>((const char*)(&lds[buf][1][0]) + boff[nf]))
#define STAGE_A(buf, h, tt) \
    gload_lds16(pAsrc + (size_t)((h) * 64) * K + (tt) * 32, &lds[buf][0][dstA + (h) * 2048])
#define STAGE_B(buf, h, tt) \
    gload_lds16(pBsrc + (size_t)((h) * 32) * K + (tt) * 32, &lds[buf][1][dstB + (h) * 1024])

    f32x4 acc[8][4] = {};
    bf16x8 a0[4], a1[4], b0[2], b1[2];

    // prologue: tile0 {A0,B0,B1,A1} (4 loads), tile1 {A0,B0,B1} (3 loads)
    STAGE_A(0, 0, 0); STAGE_B(0, 0, 0); STAGE_B(0, 1, 0); STAGE_A(0, 1, 0);
    STAGE_A(1, 0, 1); STAGE_B(1, 0, 1); STAGE_B(1, 1, 1);
    asm volatile("s_waitcnt vmcnt(3)" ::: "memory");
    PH_BARRIER();

#define MFMA_Q(AF, BF, MO, NO)                                                  \
    _Pragma("unroll") for (int mf = 0; mf < 4; ++mf)                            \
    _Pragma("unroll") for (int nf = 0; nf < 2; ++nf)                            \
        acc[(MO) + mf][(NO) + nf] = __builtin_amdgcn_mfma_f32_16x16x32_bf16(    \
            BF[nf], AF[mf], acc[(MO) + mf][(NO) + nf], 0, 0, 0);

    #pragma unroll 2
    for (int tt = 0; tt < NT; ++tt) {
        int buf = tt & 1;
        // ---- ph0: q00 ----
        #pragma unroll
        for (int mf = 0; mf < 4; ++mf) a0[mf] = LD_A(buf, 0, mf);
        #pragma unroll
        for (int nf = 0; nf < 2; ++nf) b0[nf] = LD_B(buf, nf);
        if (tt + 1 < NT) STAGE_A(buf ^ 1, 1, tt + 1);
        PH_BARRIER();
        asm volatile("s_waitcnt lgkmcnt(0)" ::: "memory");
        __builtin_amdgcn_sched_barrier(0);
        __builtin_amdgcn_s_setprio(1);
        MFMA_Q(a0, b0, 0, 0)
        __builtin_amdgcn_s_setprio(0);
        PH_BARRIER();
        // ---- ph1: q01 ----
        #pragma unroll
        for (int nf = 0; nf < 2; ++nf) b1[nf] = LD_B(buf, nf + 2);
        if (tt + 2 < NT) STAGE_A(buf, 0, tt + 2);
        PH_BARRIER();
        asm volatile("s_waitcnt lgkmcnt(0)" ::: "memory");
        __builtin_amdgcn_sched_barrier(0);
        __builtin_amdgcn_s_setprio(1);
        MFMA_Q(a0, b1, 0, 2)
        __builtin_amdgcn_s_setprio(0);
        PH_BARRIER();
        // ---- ph2: q11 ----
        #pragma unroll
        for (int mf = 0; mf < 4; ++mf) a1[mf] = LD_A(buf, 1, mf);
        if (tt + 2 < NT) STAGE_B(buf, 0, tt + 2);
        PH_BARRIER();
        asm volatile("s_waitcnt lgkmcnt(0)" ::: "memory");
        __builtin_amdgcn_sched_barrier(0);
        __builtin_amdgcn_s_setprio(1);
        MFMA_Q(a1, b1, 4, 2)
        __builtin_amdgcn_s_setprio(0);
        PH_BARRIER();
        // ---- ph3: q10 (regs held) ----
        if (tt + 2 < NT) STAGE_B(buf, 1, tt + 2);
        PH_BARRIER();
        __builtin_amdgcn_s_setprio(1);
        MFMA_Q(a1, b0, 4, 0)
        __builtin_amdgcn_s_setprio(0);
        if (tt < NT - 2) {
            asm volatile("s_waitcnt vmcnt(3)" ::: "memory");
        } else if (tt == NT - 2) {
            asm volatile("s_waitcnt vmcnt(0)" ::: "memory");
        }
        PH_BARRIER();
    }
#undef MFMA_Q
#undef LD_A
#undef LD_B
#undef STAGE_A
#undef STAGE_B

    // ---- epilogue: exp, bf16 store, fused column sums ----
    unsigned short* Eb = E + (size_t)bz * DKDIM * DKDIM;
    int nbase = bx * 256 + wn * 64 + lg * 4;
    float csum[16];
    #pragma unroll
    for (int x = 0; x < 16; ++x) csum[x] = 0.f;
    #pragma unroll
    for (int mfg = 0; mfg < 8; ++mfg) {
        int row = by * 256 + wm * 128 + (mfg >> 2) * 64 + (mfg & 3) * 16 + lm;
        #pragma unroll
        for (int nf = 0; nf < 4; ++nf) {
            f32x4 a = acc[mfg][nf];
            float e0 = __expf(scale * a[0]);
            float e1 = __expf(scale * a[1]);
            float e2 = __expf(scale * a[2]);
            float e3 = __expf(scale * a[3]);
            csum[nf * 4 + 0] += e0;
            csum[nf * 4 + 1] += e1;
            csum[nf * 4 + 2] += e2;
            csum[nf * 4 + 3] += e3;
            ushort4 o;
            o.x = f2bf(e0); o.y = f2bf(e1); o.z = f2bf(e2); o.w = f2bf(e3);
            *reinterpret_cast<ushort4*>(&Eb[(size_t)row * N + nbase + nf * 16]) = o;
        }
    }
    #pragma unroll
    for (int x = 0; x < 16; ++x) {
        float s = csum[x];
        s += __shfl_xor(s, 1, 64);
        s += __shfl_xor(s, 2, 64);
        s += __shfl_xor(s, 4, 64);
        s += __shfl_xor(s, 8, 64);
        csum[x] = s;
    }
    float val = 0.f;
    #pragma unroll
    for (int x = 0; x < 16; ++x)
        if (lm == x) val = csum[x];
    int e = bx * 256 + wn * 64 + (lm >> 2) * 16 + lg * 4 + (lm & 3);
    rpart[((size_t)(by * 2 + wm) * BS + bz) * (size_t)DKDIM + e] = val;
}

// ---------------------------------------------------------------------------
// GEMM2: out = vp * E^T. BM=256 x BN=128, BK=64, NT=32, 8 waves (4Mx2N),
// 4 quadrant phases of 8 MFMA, counted vmcnt(5). Verified r5.
// This round: + XCD swizzle (1D grid 256 => XCD i gets batch i; vp panel
// 2MB L2-resident per XCD).
// ---------------------------------------------------------------------------
__global__ __launch_bounds__(512, 2) void gemm2_av_pipe(
    const unsigned short* __restrict__ A,   // vp [b][512][2048]
    const unsigned short* __restrict__ B,   // E  [b][2048][2048]
    float* __restrict__ C)                  // out [b][512][2048]
{
    constexpr int K = DKDIM;    // 2048
    constexpr int N = DKDIM;
    constexpr int NT = K / 64;  // 32

    int wg = blockIdx.x;                    // 0..255
    int swz = (wg & 7) * 32 + (wg >> 3);    // bijective, 256 = 8*32
    int bz = swz >> 5, rem = swz & 31, by = rem >> 4, bx = rem & 15;

    const unsigned short* Ab = A + ((size_t)bz * SEQ + by * 256) * K;
    const unsigned short* Bb = B + ((size_t)bz * DKDIM + bx * 128) * K;

    __shared__ unsigned short lds[2][256 * 64 + 128 * 64];   // A then B

    int t = threadIdx.x;
    int w = t >> 6, l = t & 63;
    int wm = w >> 1, wn = w & 1;     // 4M x 2N
    int lm = l & 15, lg = l >> 4;

    int srow = t >> 3;
    int schunk = (t & 7) ^ (srow & 7);

    int rA = (srow & 31) + ((t >> 8) << 6);
    const unsigned short* pA = Ab + (size_t)rA * K + schunk * 8;
    const unsigned short* pB = Bb + (size_t)rA * K + schunk * 8;

    int aoff[4][2], boff[4][2];
    #pragma unroll
    for (int mf = 0; mf < 4; ++mf)
        #pragma unroll
        for (int ks = 0; ks < 2; ++ks) {
            int arow = wm * 64 + mf * 16 + lm;
            int kc = ks * 4 + lg;
            aoff[mf][ks] = (arow * 64 + ((kc ^ (arow & 7)) << 3)) * 2;
            int brow = wn * 64 + mf * 16 + lm;
            boff[mf][ks] = (16384 + brow * 64 + ((kc ^ (brow & 7)) << 3)) * 2;
        }

#define LD_A2(buf, mf, ks) \
    (*reinterpret_cast<const bf16x8*>((const char*)(&lds[buf][0]) + aoff[mf][ks]))
#define LD_B2(buf, nf, ks) \
    (*reinterpret_cast<const bf16x8*>((const char*)(&lds[buf][0]) + boff[nf][ks]))
#define STAGE_A2(buf, hi, tt) do {                                             \
        const unsigned short* g = pA + (hi) * 32 * K + (tt) * 64;              \
        unsigned short* d = &lds[buf][(hi) * 2048 + ((t >> 8) << 12) + (t & 255) * 8]; \
        gload_lds16(g, d);                                                     \
        gload_lds16(g + (size_t)128 * K, d + 8192);                            \
    } while (0)
#define STAGE_B2(buf, hi, tt) do {                                             \
        const unsigned short* g = pB + (hi) * 32 * K + (tt) * 64;              \
        unsigned short* d = &lds[buf][16384 + (hi) * 2048 + ((t >> 8) << 12) + (t & 255) * 8]; \
        gload_lds16(g, d);                                                     \
    } while (0)

    f32x4 acc[4][4] = {};
    bf16x8 alo[2][2], ahi[2][2], blo[2][2], bhi[2][2];

    STAGE_A2(0, 0, 0); STAGE_A2(0, 1, 0); STAGE_B2(0, 0, 0); STAGE_B2(0, 1, 0);
    STAGE_A2(1, 0, 1); STAGE_B2(1, 0, 1); STAGE_A2(1, 1, 1);
    asm volatile("s_waitcnt vmcnt(5)" ::: "memory");
    PH_BARRIER();

#define MFMA_Q2(AF, BF, MO, NO)                                                 \
    _Pragma("unroll") for (int ks = 0; ks < 2; ++ks)                            \
    _Pragma("unroll") for (int mf = 0; mf < 2; ++mf)                            \
    _Pragma("unroll") for (int nf = 0; nf < 2; ++nf)                            \
        acc[(MO) + mf][(NO) + nf] = __builtin_amdgcn_mfma_f32_16x16x32_bf16(    \
            BF[ks][nf], AF[ks][mf], acc[(MO) + mf][(NO) + nf], 0, 0, 0);

    #pragma unroll 2
    for (int tt = 0; tt < NT; ++tt) {
        int buf = tt & 1;
        // ---- ph0: alo x blo ----
        #pragma unroll
        for (int ks = 0; ks < 2; ++ks)
            #pragma unroll
            for (int f = 0; f < 2; ++f) {
                alo[ks][f] = LD_A2(buf, f, ks);
                blo[ks][f] = LD_B2(buf, f, ks);
            }
        if (tt + 1 < NT) STAGE_B2(buf ^ 1, 1, tt + 1);
        PH_BARRIER();
        asm volatile("s_waitcnt lgkmcnt(0)" ::: "memory");
        __builtin_amdgcn_sched_barrier(0);
        __builtin_amdgcn_s_setprio(1);
        MFMA_Q2(alo, blo, 0, 0)
        __builtin_amdgcn_s_setprio(0);
        PH_BARRIER();
        // ---- ph1: alo x bhi ----
        #pragma unroll
        for (int ks = 0; ks < 2; ++ks)
            #pragma unroll
            for (int f = 0; f < 2; ++f) bhi[ks][f] = LD_B2(buf, f + 2, ks);
        if (tt + 2 < NT) STAGE_A2(buf, 0, tt + 2);
        PH_BARRIER();
        asm volatile("s_waitcnt lgkmcnt(0)" ::: "memory");
        __builtin_amdgcn_sched_barrier(0);
        __builtin_amdgcn_s_setprio(1);
        MFMA_Q2(alo, bhi, 0, 2)
        __builtin_amdgcn_s_setprio(0);
        PH_BARRIER();
        // ---- ph2: ahi x bhi ----
        #pragma unroll
        for (int ks = 0; ks < 2; ++ks)
            #pragma unroll
            for (int f = 0; f < 2; ++f) ahi[ks][f] = LD_A2(buf, f + 2, ks);
        if (tt + 2 < NT) STAGE_B2(buf, 0, tt + 2);
        PH_BARRIER();
        asm volatile("s_waitcnt lgkmcnt(0)" ::: "memory");
        __builtin_amdgcn_sched_barrier(0);
        __builtin_amdgcn_s_setprio(1);
        MFMA_Q2(ahi, bhi, 2, 2)
        __builtin_amdgcn_s_setprio(0);
        PH_BARRIER();
        // ---- ph3: ahi x blo (regs held) ----
        if (tt + 2 < NT) STAGE_A2(buf, 1, tt + 2);
        PH_BARRIER();
        __builtin_amdgcn_s_setprio(1);
        MFMA_Q2(ahi, blo, 2, 0)
        __builtin_amdgcn_s_setprio(0);
        if (tt < NT - 2) {
            asm volatile("s_waitcnt vmcnt(5)" ::: "memory");
        } else if (tt == NT - 2) {
            asm volatile("s_waitcnt vmcnt(0)" ::: "memory");
        }
        PH_BARRIER();
    }
#undef MFMA_Q2
#undef LD_A2
#undef LD_B2
#undef STAGE_A2
#undef STAGE_B2

    float* Cf = C + (size_t)bz * SEQ * DKDIM;
    int mbase = by * 256 + wm * 64 + lm;
    int nbase = bx * 128 + wn * 64 + lg * 4;
    #pragma unroll
    for (int i = 0; i < 4; ++i)
        #pragma unroll
        for (int j = 0; j < 4; ++j)
            *reinterpret_cast<f32x4*>(&Cf[(size_t)(mbase + i * 16) * N + nbase + j * 16]) = acc[i][j];
}

// ---------------------------------------------------------------------------
// rinv[b][e] = 1 / sum over 16 partials
// ---------------------------------------------------------------------------
__global__ __launch_bounds__(256) void colsum_finish(
    const float* __restrict__ rpart, float* __restrict__ rinv)
{
    int i = blockIdx.x * 256 + threadIdx.x;
    float s = 0.f;
    #pragma unroll
    for (int p = 0; p < 16; ++p) s += rpart[(size_t)p * BS * DKDIM + i];
    rinv[i] = 1.0f / s;
}

// ---------------------------------------------------------------------------
// v'[b][s][e] = bf16( v[b][s][e] * rinv[b][e] )
// ---------------------------------------------------------------------------
__global__ __launch_bounds__(256) void vprime_kernel(
    const float* __restrict__ v, const float* __restrict__ rinv,
    unsigned short* __restrict__ vp)
{
    size_t i4 = ((size_t)blockIdx.x * 256 + threadIdx.x) * 4;
    int e = (int)(i4 & (DKDIM - 1));
    int b = (int)(i4 >> 20);
    float4 v4 = *reinterpret_cast<const float4*>(&v[i4]);
    float4 r4 = *reinterpret_cast<const float4*>(&rinv[(size_t)b * DKDIM + e]);
    ushort4 o;
    o.x = f2bf(v4.x * r4.x);
    o.y = f2bf(v4.y * r4.y);
    o.z = f2bf(v4.z * r4.z);
    o.w = f2bf(v4.w * r4.w);
    *reinterpret_cast<ushort4*>(&vp[i4]) = o;
}

extern "C" void kernel_launch(void* const* d_in, const int* in_sizes, int n_in,
                              void* d_out, int out_size, void* d_ws, size_t ws_size,
                              hipStream_t stream) {
    const float* q = (const float*)d_in[0];
    const float* k = (const float*)d_in[1];
    const float* v = (const float*)d_in[2];
    float* out = (float*)d_out;

    char* ws = (char*)d_ws;
    unsigned short* qT = (unsigned short*)(ws);                        // 16 MB
    unsigned short* kT = (unsigned short*)(ws + 16777216);             // 16 MB
    unsigned short* E  = (unsigned short*)(ws + 33554432);             // 64 MB
    float* rpart       = (float*)(ws + 100663296);                     // 1 MB
    float* rinv        = (float*)(ws + 102760448);                     // 64 KB
    unsigned short* vp = (unsigned short*)(ws + 103809024);            // 16 MB

    const float scale = 0.022097086912079608f;  // 1/sqrt(2048)

    transpose_conv_kernel<<<dim3(DKDIM / 64, SEQ / 64, 2 * BS), 256, 0, stream>>>(q, k, qT, kT);

    gemm1_qk_exp<<<dim3(512), 512, 0, stream>>>(qT, kT, E, rpart, scale);

    colsum_finish<<<dim3(BS * DKDIM / 256), 256, 0, stream>>>(rpart, rinv);

    vprime_kernel<<<dim3(BS * SEQ * DKDIM / 1024), 256, 0, stream>>>(v, rinv, vp);

    gemm2_av_pipe<<<dim3(256), 512, 0, stream>>>(vp, E, out);
}

// Round 7
// 130.156 us; speedup vs baseline: 2.9789x; 2.9789x over previous
//
#include <hip/hip_runtime.h>
#include <hip/hip_bf16.h>

#define BS 8
#define SEQ 512
#define DKDIM 2048

using bf16x8 = __attribute__((ext_vector_type(8))) __bf16;
using f32x4  = __attribute__((ext_vector_type(4))) float;

__device__ __forceinline__ unsigned short f2bf(float f) {
    unsigned int u = __builtin_bit_cast(unsigned int, f);
    u += 0x7FFFu + ((u >> 16) & 1u);
    return (unsigned short)(u >> 16);
}

__device__ __forceinline__ void gload_lds16(const unsigned short* g, unsigned short* l) {
    __builtin_amdgcn_global_load_lds(
        (const __attribute__((address_space(1))) unsigned int*)g,
        (__attribute__((address_space(3))) unsigned int*)l, 16, 0, 0);
}

#define PH_BARRIER() asm volatile("s_barrier" ::: "memory")

// ---------------------------------------------------------------------------
// Transpose+convert: in [SEQ][DK] f32 (per batch) -> out [DK][SEQ] bf16
// ---------------------------------------------------------------------------
__global__ __launch_bounds__(256) void transpose_conv_kernel(
    const float* __restrict__ q, const float* __restrict__ k,
    unsigned short* __restrict__ qT, unsigned short* __restrict__ kT)
{
    int z = blockIdx.z;
    const float* in = (z < BS) ? q : k;
    unsigned short* out = (z < BS) ? qT : kT;
    int b = z & (BS - 1);
    in  += (size_t)b * SEQ * DKDIM;
    out += (size_t)b * DKDIM * SEQ;
    int s0 = blockIdx.y * 64;
    int d0 = blockIdx.x * 64;
    __shared__ unsigned short tile[64][66];
    int t = threadIdx.x;
    int tr  = t >> 4;
    int tc4 = (t & 15) * 4;
    #pragma unroll
    for (int p = 0; p < 4; ++p) {
        int s = p * 16 + tr;
        float4 v4 = *reinterpret_cast<const float4*>(&in[(size_t)(s0 + s) * DKDIM + d0 + tc4]);
        tile[s][tc4 + 0] = f2bf(v4.x);
        tile[s][tc4 + 1] = f2bf(v4.y);
        tile[s][tc4 + 2] = f2bf(v4.z);
        tile[s][tc4 + 3] = f2bf(v4.w);
    }
    __syncthreads();
    #pragma unroll
    for (int p = 0; p < 4; ++p) {
        int d = p * 16 + tr;
        ushort4 o;
        o.x = tile[tc4 + 0][d];
        o.y = tile[tc4 + 1][d];
        o.z = tile[tc4 + 2][d];
        o.w = tile[tc4 + 3][d];
        *reinterpret_cast<ushort4*>(&out[(size_t)(d0 + d) * SEQ + s0 + tc4]) = o;
    }
}

// ---------------------------------------------------------------------------
// GEMM1: E = exp(scale*(qT kT^T)), bf16, + fused column partial sums.
// PORT OF THE PROVEN gemm2 SHELL (r5-verified schedule, stage slots, and
// vmcnt constants, byte-identical): BM=256 x BN=128, BK=64, NT=8, 8 waves
// (4Mx2N), wave tile 64x64, acc[4][4], 4 quadrant phases of 8 MFMA,
// counted vmcnt(5)/vmcnt(0)@NT-2.  LDS 96KB.  launch_bounds(512,2) (r6
// lesson: min-waves=4 capped VGPR at 64 -> acc spilled to scratch, 6-12x
// memory traffic).
// Grid 1024 = 8 batches x (8 by x 16 bx), XCD-bijective swizzle: XCD i
// owns batch i => its 4MB qT+kT panel set is L2-resident.
// Epilogue: exp, packed ushort4 E-store, fused per-wave column sums ->
// rpart[by*4+wm] (32 partials).
// ---------------------------------------------------------------------------
__global__ __launch_bounds__(512, 2) void gemm1_qk_exp(
    const unsigned short* __restrict__ A,   // qT [b][2048][512]
    const unsigned short* __restrict__ B,   // kT [b][2048][512]
    unsigned short* __restrict__ E,         // [b][2048][2048]
    float* __restrict__ rpart,              // [32][BS][2048]
    float scale)
{
    constexpr int K = SEQ;      // 512
    constexpr int N = DKDIM;    // 2048
    constexpr int NT = K / 64;  // 8

    int wg = blockIdx.x;                     // 0..1023
    int swz = (wg & 7) * 128 + (wg >> 3);    // bijective (1024 = 8*128)
    int bz = swz >> 7, rem = swz & 127, by = rem >> 4, bx = rem & 15;

    const unsigned short* Ab = A + ((size_t)bz * DKDIM + by * 256) * K;
    const unsigned short* Bb = B + ((size_t)bz * DKDIM + bx * 128) * K;

    __shared__ unsigned short lds[2][256 * 64 + 128 * 64];   // A then B

    int t = threadIdx.x;
    int w = t >> 6, l = t & 63;
    int wm = w >> 1, wn = w & 1;     // 4M x 2N
    int lm = l & 15, lg = l >> 4;

    int srow = t >> 3;
    int schunk = (t & 7) ^ (srow & 7);

    int rA = (srow & 31) + ((t >> 8) << 6);
    const unsigned short* pA = Ab + (size_t)rA * K + schunk * 8;
    const unsigned short* pB = Bb + (size_t)rA * K + schunk * 8;

    int aoff[4][2], boff[4][2];
    #pragma unroll
    for (int mf = 0; mf < 4; ++mf)
        #pragma unroll
        for (int ks = 0; ks < 2; ++ks) {
            int kc = ks * 4 + lg;
            int arow = wm * 64 + mf * 16 + lm;
            aoff[mf][ks] = (arow * 64 + ((kc ^ (arow & 7)) << 3)) * 2;
            int brow = wn * 64 + mf * 16 + lm;
            boff[mf][ks] = (16384 + brow * 64 + ((kc ^ (brow & 7)) << 3)) * 2;
        }

#define LD_A1(buf, mf, ks) \
    (*reinterpret_cast<const bf16x8*>((const char*)(&lds[buf][0]) + aoff[mf][ks]))
#define LD_B1(buf, nf, ks) \
    (*reinterpret_cast<const bf16x8*>((const char*)(&lds[buf][0]) + boff[nf][ks]))
#define STAGE_A1(buf, hi, tt) do {                                             \
        const unsigned short* g = pA + (hi) * 32 * K + (tt) * 64;              \
        unsigned short* d = &lds[buf][(hi) * 2048 + ((t >> 8) << 12) + (t & 255) * 8]; \
        gload_lds16(g, d);                                                     \
        gload_lds16(g + (size_t)128 * K, d + 8192);                            \
    } while (0)
#define STAGE_B1(buf, hi, tt) do {                                             \
        const unsigned short* g = pB + (hi) * 32 * K + (tt) * 64;              \
        unsigned short* d = &lds[buf][16384 + (hi) * 2048 + ((t >> 8) << 12) + (t & 255) * 8]; \
        gload_lds16(g, d);                                                     \
    } while (0)

    f32x4 acc[4][4] = {};
    bf16x8 alo[2][2], ahi[2][2], blo[2][2], bhi[2][2];

    STAGE_A1(0, 0, 0); STAGE_A1(0, 1, 0); STAGE_B1(0, 0, 0); STAGE_B1(0, 1, 0);
    STAGE_A1(1, 0, 1); STAGE_B1(1, 0, 1); STAGE_A1(1, 1, 1);
    asm volatile("s_waitcnt vmcnt(5)" ::: "memory");
    PH_BARRIER();

#define MFMA_Q1(AF, BF, MO, NO)                                                 \
    _Pragma("unroll") for (int ks = 0; ks < 2; ++ks)                            \
    _Pragma("unroll") for (int mf = 0; mf < 2; ++mf)                            \
    _Pragma("unroll") for (int nf = 0; nf < 2; ++nf)                            \
        acc[(MO) + mf][(NO) + nf] = __builtin_amdgcn_mfma_f32_16x16x32_bf16(    \
            BF[ks][nf], AF[ks][mf], acc[(MO) + mf][(NO) + nf], 0, 0, 0);

    #pragma unroll 2
    for (int tt = 0; tt < NT; ++tt) {
        int buf = tt & 1;
        // ---- ph0: alo x blo ----
        #pragma unroll
        for (int ks = 0; ks < 2; ++ks)
            #pragma unroll
            for (int f = 0; f < 2; ++f) {
                alo[ks][f] = LD_A1(buf, f, ks);
                blo[ks][f] = LD_B1(buf, f, ks);
            }
        if (tt + 1 < NT) STAGE_B1(buf ^ 1, 1, tt + 1);
        PH_BARRIER();
        asm volatile("s_waitcnt lgkmcnt(0)" ::: "memory");
        __builtin_amdgcn_sched_barrier(0);
        __builtin_amdgcn_s_setprio(1);
        MFMA_Q1(alo, blo, 0, 0)
        __builtin_amdgcn_s_setprio(0);
        PH_BARRIER();
        // ---- ph1: alo x bhi ----
        #pragma unroll
        for (int ks = 0; ks < 2; ++ks)
            #pragma unroll
            for (int f = 0; f < 2; ++f) bhi[ks][f] = LD_B1(buf, f + 2, ks);
        if (tt + 2 < NT) STAGE_A1(buf, 0, tt + 2);
        PH_BARRIER();
        asm volatile("s_waitcnt lgkmcnt(0)" ::: "memory");
        __builtin_amdgcn_sched_barrier(0);
        __builtin_amdgcn_s_setprio(1);
        MFMA_Q1(alo, bhi, 0, 2)
        __builtin_amdgcn_s_setprio(0);
        PH_BARRIER();
        // ---- ph2: ahi x bhi ----
        #pragma unroll
        for (int ks = 0; ks < 2; ++ks)
            #pragma unroll
            for (int f = 0; f < 2; ++f) ahi[ks][f] = LD_A1(buf, f + 2, ks);
        if (tt + 2 < NT) STAGE_B1(buf, 0, tt + 2);
        PH_BARRIER();
        asm volatile("s_waitcnt lgkmcnt(0)" ::: "memory");
        __builtin_amdgcn_sched_barrier(0);
        __builtin_amdgcn_s_setprio(1);
        MFMA_Q1(ahi, bhi, 2, 2)
        __builtin_amdgcn_s_setprio(0);
        PH_BARRIER();
        // ---- ph3: ahi x blo (regs held) ----
        if (tt + 2 < NT) STAGE_A1(buf, 1, tt + 2);
        PH_BARRIER();
        __builtin_amdgcn_s_setprio(1);
        MFMA_Q1(ahi, blo, 2, 0)
        __builtin_amdgcn_s_setprio(0);
        if (tt < NT - 2) {
            asm volatile("s_waitcnt vmcnt(5)" ::: "memory");
        } else if (tt == NT - 2) {
            asm volatile("s_waitcnt vmcnt(0)" ::: "memory");
        }
        PH_BARRIER();
    }
#undef MFMA_Q1
#undef LD_A1
#undef LD_B1
#undef STAGE_A1
#undef STAGE_B1

    // ---- epilogue: exp, packed bf16 store, fused column sums ----
    unsigned short* Eb = E + (size_t)bz * DKDIM * DKDIM;
    int nbase = bx * 128 + wn * 64 + lg * 4;
    float csum[16];
    #pragma unroll
    for (int x = 0; x < 16; ++x) csum[x] = 0.f;
    #pragma unroll
    for (int mf = 0; mf < 4; ++mf) {
        int row = by * 256 + wm * 64 + mf * 16 + lm;
        #pragma unroll
        for (int nf = 0; nf < 4; ++nf) {
            f32x4 a = acc[mf][nf];
            float e0 = __expf(scale * a[0]);
            float e1 = __expf(scale * a[1]);
            float e2 = __expf(scale * a[2]);
            float e3 = __expf(scale * a[3]);
            csum[nf * 4 + 0] += e0;
            csum[nf * 4 + 1] += e1;
            csum[nf * 4 + 2] += e2;
            csum[nf * 4 + 3] += e3;
            ushort4 o;
            o.x = f2bf(e0); o.y = f2bf(e1); o.z = f2bf(e2); o.w = f2bf(e3);
            *reinterpret_cast<ushort4*>(&Eb[(size_t)row * N + nbase + nf * 16]) = o;
        }
    }
    #pragma unroll
    for (int x = 0; x < 16; ++x) {
        float s = csum[x];
        s += __shfl_xor(s, 1, 64);
        s += __shfl_xor(s, 2, 64);
        s += __shfl_xor(s, 4, 64);
        s += __shfl_xor(s, 8, 64);
        csum[x] = s;
    }
    float val = 0.f;
    #pragma unroll
    for (int x = 0; x < 16; ++x)
        if (lm == x) val = csum[x];
    int e = bx * 128 + wn * 64 + (lm >> 2) * 16 + lg * 4 + (lm & 3);
    rpart[((size_t)(by * 4 + wm) * BS + bz) * (size_t)DKDIM + e] = val;
}

// ---------------------------------------------------------------------------
// GEMM2: out = vp * E^T. BM=256 x BN=128, BK=64, NT=32, 8 waves (4Mx2N),
// 4 quadrant phases of 8 MFMA, counted vmcnt(5). Exact r5-verified version.
// ---------------------------------------------------------------------------
__global__ __launch_bounds__(512, 2) void gemm2_av_pipe(
    const unsigned short* __restrict__ A,   // vp [b][512][2048]
    const unsigned short* __restrict__ B,   // E  [b][2048][2048]
    float* __restrict__ C)                  // out [b][512][2048]
{
    constexpr int K = DKDIM;    // 2048
    constexpr int N = DKDIM;
    constexpr int NT = K / 64;  // 32

    int b = blockIdx.z;
    const unsigned short* Ab = A + ((size_t)b * SEQ + blockIdx.y * 256) * K;
    const unsigned short* Bb = B + ((size_t)b * DKDIM + blockIdx.x * 128) * K;

    __shared__ unsigned short lds[2][256 * 64 + 128 * 64];   // A then B

    int t = threadIdx.x;
    int w = t >> 6, l = t & 63;
    int wm = w >> 1, wn = w & 1;     // 4M x 2N
    int lm = l & 15, lg = l >> 4;

    int srow = t >> 3;
    int schunk = (t & 7) ^ (srow & 7);

    int rA = (srow & 31) + ((t >> 8) << 6);
    const unsigned short* pA = Ab + (size_t)rA * K + schunk * 8;
    const unsigned short* pB = Bb + (size_t)rA * K + schunk * 8;

    int aoff[4][2], boff[4][2];
    #pragma unroll
    for (int mf = 0; mf < 4; ++mf)
        #pragma unroll
        for (int ks = 0; ks < 2; ++ks) {
            int arow = wm * 64 + mf * 16 + lm;
            int kc = ks * 4 + lg;
            aoff[mf][ks] = (arow * 64 + ((kc ^ (arow & 7)) << 3)) * 2;
            int brow = wn * 64 + mf * 16 + lm;
            boff[mf][ks] = (16384 + brow * 64 + ((kc ^ (brow & 7)) << 3)) * 2;
        }

#define LD_A2(buf, mf, ks) \
    (*reinterpret_cast<const bf16x8*>((const char*)(&lds[buf][0]) + aoff[mf][ks]))
#define LD_B2(buf, nf, ks) \
    (*reinterpret_cast<const bf16x8*>((const char*)(&lds[buf][0]) + boff[nf][ks]))
#define STAGE_A2(buf, hi, tt) do {                                             \
        const unsigned short* g = pA + (hi) * 32 * K + (tt) * 64;              \
        unsigned short* d = &lds[buf][(hi) * 2048 + ((t >> 8) << 12) + (t & 255) * 8]; \
        gload_lds16(g, d);                                                     \
        gload_lds16(g + (size_t)128 * K, d + 8192);                            \
    } while (0)
#define STAGE_B2(buf, hi, tt) do {                                             \
        const unsigned short* g = pB + (hi) * 32 * K + (tt) * 64;              \
        unsigned short* d = &lds[buf][16384 + (hi) * 2048 + ((t >> 8) << 12) + (t & 255) * 8]; \
        gload_lds16(g, d);                                                     \
    } while (0)

    f32x4 acc[4][4] = {};
    bf16x8 alo[2][2], ahi[2][2], blo[2][2], bhi[2][2];

    STAGE_A2(0, 0, 0); STAGE_A2(0, 1, 0); STAGE_B2(0, 0, 0); STAGE_B2(0, 1, 0);
    STAGE_A2(1, 0, 1); STAGE_B2(1, 0, 1); STAGE_A2(1, 1, 1);
    asm volatile("s_waitcnt vmcnt(5)" ::: "memory");
    PH_BARRIER();

#define MFMA_Q2(AF, BF, MO, NO)                                                 \
    _Pragma("unroll") for (int ks = 0; ks < 2; ++ks)                            \
    _Pragma("unroll") for (int mf = 0; mf < 2; ++mf)                            \
    _Pragma("unroll") for (int nf = 0; nf < 2; ++nf)                            \
        acc[(MO) + mf][(NO) + nf] = __builtin_amdgcn_mfma_f32_16x16x32_bf16(    \
            BF[ks][nf], AF[ks][mf], acc[(MO) + mf][(NO) + nf], 0, 0, 0);

    #pragma unroll 2
    for (int tt = 0; tt < NT; ++tt) {
        int buf = tt & 1;
        // ---- ph0: alo x blo ----
        #pragma unroll
        for (int ks = 0; ks < 2; ++ks)
            #pragma unroll
            for (int f = 0; f < 2; ++f) {
                alo[ks][f] = LD_A2(buf, f, ks);
                blo[ks][f] = LD_B2(buf, f, ks);
            }
        if (tt + 1 < NT) STAGE_B2(buf ^ 1, 1, tt + 1);
        PH_BARRIER();
        asm volatile("s_waitcnt lgkmcnt(0)" ::: "memory");
        __builtin_amdgcn_sched_barrier(0);
        __builtin_amdgcn_s_setprio(1);
        MFMA_Q2(alo, blo, 0, 0)
        __builtin_amdgcn_s_setprio(0);
        PH_BARRIER();
        // ---- ph1: alo x bhi ----
        #pragma unroll
        for (int ks = 0; ks < 2; ++ks)
            #pragma unroll
            for (int f = 0; f < 2; ++f) bhi[ks][f] = LD_B2(buf, f + 2, ks);
        if (tt + 2 < NT) STAGE_A2(buf, 0, tt + 2);
        PH_BARRIER();
        asm volatile("s_waitcnt lgkmcnt(0)" ::: "memory");
        __builtin_amdgcn_sched_barrier(0);
        __builtin_amdgcn_s_setprio(1);
        MFMA_Q2(alo, bhi, 0, 2)
        __builtin_amdgcn_s_setprio(0);
        PH_BARRIER();
        // ---- ph2: ahi x bhi ----
        #pragma unroll
        for (int ks = 0; ks < 2; ++ks)
            #pragma unroll
            for (int f = 0; f < 2; ++f) ahi[ks][f] = LD_A2(buf, f + 2, ks);
        if (tt + 2 < NT) STAGE_B2(buf, 0, tt + 2);
        PH_BARRIER();
        asm volatile("s_waitcnt lgkmcnt(0)" ::: "memory");
        __builtin_amdgcn_sched_barrier(0);
        __builtin_amdgcn_s_setprio(1);
        MFMA_Q2(ahi, bhi, 2, 2)
        __builtin_amdgcn_s_setprio(0);
        PH_BARRIER();
        // ---- ph3: ahi x blo (regs held) ----
        if (tt + 2 < NT) STAGE_A2(buf, 1, tt + 2);
        PH_BARRIER();
        __builtin_amdgcn_s_setprio(1);
        MFMA_Q2(ahi, blo, 2, 0)
        __builtin_amdgcn_s_setprio(0);
        if (tt < NT - 2) {
            asm volatile("s_waitcnt vmcnt(5)" ::: "memory");
        } else if (tt == NT - 2) {
            asm volatile("s_waitcnt vmcnt(0)" ::: "memory");
        }
        PH_BARRIER();
    }
#undef MFMA_Q2
#undef LD_A2
#undef LD_B2
#undef STAGE_A2
#undef STAGE_B2

    float* Cf = C + (size_t)b * SEQ * DKDIM;
    int mbase = blockIdx.y * 256 + wm * 64 + lm;
    int nbase = blockIdx.x * 128 + wn * 64 + lg * 4;
    #pragma unroll
    for (int i = 0; i < 4; ++i)
        #pragma unroll
        for (int j = 0; j < 4; ++j)
            *reinterpret_cast<f32x4*>(&Cf[(size_t)(mbase + i * 16) * N + nbase + j * 16]) = acc[i][j];
}

// ---------------------------------------------------------------------------
// rinv[b][e] = 1 / sum over 32 partials
// ---------------------------------------------------------------------------
__global__ __launch_bounds__(256) void colsum_finish(
    const float* __restrict__ rpart, float* __restrict__ rinv)
{
    int i = blockIdx.x * 256 + threadIdx.x;
    float s = 0.f;
    #pragma unroll
    for (int p = 0; p < 32; ++p) s += rpart[(size_t)p * BS * DKDIM + i];
    rinv[i] = 1.0f / s;
}

// ---------------------------------------------------------------------------
// v'[b][s][e] = bf16( v[b][s][e] * rinv[b][e] )
// ---------------------------------------------------------------------------
__global__ __launch_bounds__(256) void vprime_kernel(
    const float* __restrict__ v, const float* __restrict__ rinv,
    unsigned short* __restrict__ vp)
{
    size_t i4 = ((size_t)blockIdx.x * 256 + threadIdx.x) * 4;
    int e = (int)(i4 & (DKDIM - 1));
    int b = (int)(i4 >> 20);
    float4 v4 = *reinterpret_cast<const float4*>(&v[i4]);
    float4 r4 = *reinterpret_cast<const float4*>(&rinv[(size_t)b * DKDIM + e]);
    ushort4 o;
    o.x = f2bf(v4.x * r4.x);
    o.y = f2bf(v4.y * r4.y);
    o.z = f2bf(v4.z * r4.z);
    o.w = f2bf(v4.w * r4.w);
    *reinterpret_cast<ushort4*>(&vp[i4]) = o;
}

extern "C" void kernel_launch(void* const* d_in, const int* in_sizes, int n_in,
                              void* d_out, int out_size, void* d_ws, size_t ws_size,
                              hipStream_t stream) {
    const float* q = (const float*)d_in[0];
    const float* k = (const float*)d_in[1];
    const float* v = (const float*)d_in[2];
    float* out = (float*)d_out;

    char* ws = (char*)d_ws;
    unsigned short* qT = (unsigned short*)(ws);                        // 16 MB
    unsigned short* kT = (unsigned short*)(ws + 16777216);             // 16 MB
    unsigned short* E  = (unsigned short*)(ws + 33554432);             // 64 MB
    float* rpart       = (float*)(ws + 100663296);                     // 2 MB (32x8x2048 f32)
    float* rinv        = (float*)(ws + 102760448);                     // 64 KB
    unsigned short* vp = (unsigned short*)(ws + 103809024);            // 16 MB

    const float scale = 0.022097086912079608f;  // 1/sqrt(2048)

    transpose_conv_kernel<<<dim3(DKDIM / 64, SEQ / 64, 2 * BS), 256, 0, stream>>>(q, k, qT, kT);

    gemm1_qk_exp<<<dim3(1024), 512, 0, stream>>>(qT, kT, E, rpart, scale);

    colsum_finish<<<dim3(BS * DKDIM / 256), 256, 0, stream>>>(rpart, rinv);

    vprime_kernel<<<dim3(BS * SEQ * DKDIM / 1024), 256, 0, stream>>>(v, rinv, vp);

    gemm2_av_pipe<<<dim3(DKDIM / 128, SEQ / 256, BS), 512, 0, stream>>>(vp, E, out);
}

// Round 8
// 121.300 us; speedup vs baseline: 3.1964x; 1.0730x over previous
//
#include <hip/hip_runtime.h>
#include <hip/hip_bf16.h>

#define BS 8
#define SEQ 512
#define DKDIM 2048

using bf16x8 = __attribute__((ext_vector_type(8))) __bf16;
using f32x4  = __attribute__((ext_vector_type(4))) float;

__device__ __forceinline__ unsigned short f2bf(float f) {
    unsigned int u = __builtin_bit_cast(unsigned int, f);
    u += 0x7FFFu + ((u >> 16) & 1u);
    return (unsigned short)(u >> 16);
}

__device__ __forceinline__ void gload_lds16(const unsigned short* g, unsigned short* l) {
    __builtin_amdgcn_global_load_lds(
        (const __attribute__((address_space(1))) unsigned int*)g,
        (__attribute__((address_space(3))) unsigned int*)l, 16, 0, 0);
}

#define PH_BARRIER() asm volatile("s_barrier" ::: "memory")

// ---------------------------------------------------------------------------
// Transpose+convert: in [SEQ][DK] f32 (per batch) -> out [DK][SEQ] bf16
// ---------------------------------------------------------------------------
__global__ __launch_bounds__(256) void transpose_conv_kernel(
    const float* __restrict__ q, const float* __restrict__ k,
    unsigned short* __restrict__ qT, unsigned short* __restrict__ kT)
{
    int z = blockIdx.z;
    const float* in = (z < BS) ? q : k;
    unsigned short* out = (z < BS) ? qT : kT;
    int b = z & (BS - 1);
    in  += (size_t)b * SEQ * DKDIM;
    out += (size_t)b * DKDIM * SEQ;
    int s0 = blockIdx.y * 64;
    int d0 = blockIdx.x * 64;
    __shared__ unsigned short tile[64][66];
    int t = threadIdx.x;
    int tr  = t >> 4;
    int tc4 = (t & 15) * 4;
    #pragma unroll
    for (int p = 0; p < 4; ++p) {
        int s = p * 16 + tr;
        float4 v4 = *reinterpret_cast<const float4*>(&in[(size_t)(s0 + s) * DKDIM + d0 + tc4]);
        tile[s][tc4 + 0] = f2bf(v4.x);
        tile[s][tc4 + 1] = f2bf(v4.y);
        tile[s][tc4 + 2] = f2bf(v4.z);
        tile[s][tc4 + 3] = f2bf(v4.w);
    }
    __syncthreads();
    #pragma unroll
    for (int p = 0; p < 4; ++p) {
        int d = p * 16 + tr;
        ushort4 o;
        o.x = tile[tc4 + 0][d];
        o.y = tile[tc4 + 1][d];
        o.z = tile[tc4 + 2][d];
        o.w = tile[tc4 + 3][d];
        *reinterpret_cast<ushort4*>(&out[(size_t)(d0 + d) * SEQ + s0 + tc4]) = o;
    }
}

// ---------------------------------------------------------------------------
// GEMM1 (PERSISTENT): E = exp(scale*(qT kT^T)), bf16, + fused col partials.
// Grid 256 = 1 block/CU, single round. Each block owns 4 output tiles
// (by fixed, bx = bxg*4 + g, g=0..3), flattened into ONE 32-k-tile pipeline
// using the verified r5/r7 shell (BM=256 BN=128 BK=64, 8 waves 4Mx2N,
// 4 quadrant phases, counted vmcnt(5), vmcnt(0) only at global gtt==30).
// buf = tt&1 is g-invariant (8 even). A panel identical across g (restaged
// with identical bytes; liveness pattern uniform in gtt, proof unchanged).
// B panel pointer advances 128 rows per g; stages at tt=6,7 target tile
// g+1's k-tiles 0,1 via pB_nxt. Per-tile epilogue runs inside the pipeline
// (no LDS touch; its stores retire during next tile's ph0-ph2).
// XCD swizzle: XCD i owns batch i (4MB qT+kT L2-resident).
// ---------------------------------------------------------------------------
__global__ __launch_bounds__(512, 2) void gemm1_qk_exp(
    const unsigned short* __restrict__ A,   // qT [b][2048][512]
    const unsigned short* __restrict__ B,   // kT [b][2048][512]
    unsigned short* __restrict__ E,         // [b][2048][2048]
    float* __restrict__ rpart,              // [32][BS][2048]
    float scale)
{
    constexpr int K = SEQ;      // 512
    constexpr int N = DKDIM;    // 2048

    int wg = blockIdx.x;                    // 0..255
    int swz = (wg & 7) * 32 + (wg >> 3);    // bijective (256 = 8*32)
    int bz = swz >> 5, rem = swz & 31, by = rem >> 2, bxg = rem & 3;

    const unsigned short* Ab = A + ((size_t)bz * DKDIM + by * 256) * K;
    const unsigned short* Bb = B + ((size_t)bz * DKDIM + bxg * 512) * K;

    __shared__ unsigned short lds[2][256 * 64 + 128 * 64];   // A then B

    int t = threadIdx.x;
    int w = t >> 6, l = t & 63;
    int wm = w >> 1, wn = w & 1;     // 4M x 2N
    int lm = l & 15, lg = l >> 4;

    int srow = t >> 3;
    int schunk = (t & 7) ^ (srow & 7);

    int rA = (srow & 31) + ((t >> 8) << 6);
    const unsigned short* pA = Ab + (size_t)rA * K + schunk * 8;
    const unsigned short* pB = Bb + (size_t)rA * K + schunk * 8;   // advances 128*K per g

    int aoff[4][2], boff[4][2];
    #pragma unroll
    for (int mf = 0; mf < 4; ++mf)
        #pragma unroll
        for (int ks = 0; ks < 2; ++ks) {
            int kc = ks * 4 + lg;
            int arow = wm * 64 + mf * 16 + lm;
            aoff[mf][ks] = (arow * 64 + ((kc ^ (arow & 7)) << 3)) * 2;
            int brow = wn * 64 + mf * 16 + lm;
            boff[mf][ks] = (16384 + brow * 64 + ((kc ^ (brow & 7)) << 3)) * 2;
        }

#define LD_A1(buf, mf, ks) \
    (*reinterpret_cast<const bf16x8*>((const char*)(&lds[buf][0]) + aoff[mf][ks]))
#define LD_B1(buf, nf, ks) \
    (*reinterpret_cast<const bf16x8*>((const char*)(&lds[buf][0]) + boff[nf][ks]))
#define STAGE_A1(buf, hi, tt) do {                                             \
        const unsigned short* gsrc = pA + (hi) * 32 * K + (tt) * 64;           \
        unsigned short* d = &lds[buf][(hi) * 2048 + ((t >> 8) << 12) + (t & 255) * 8]; \
        gload_lds16(gsrc, d);                                                  \
        gload_lds16(gsrc + (size_t)128 * K, d + 8192);                         \
    } while (0)
#define STAGE_B1(buf, hi, ptr, tt) do {                                        \
        const unsigned short* gsrc = (ptr) + (hi) * 32 * K + (tt) * 64;        \
        unsigned short* d = &lds[buf][16384 + (hi) * 2048 + ((t >> 8) << 12) + (t & 255) * 8]; \
        gload_lds16(gsrc, d);                                                  \
    } while (0)

    f32x4 acc[4][4] = {};
    bf16x8 alo[2][2], ahi[2][2], blo[2][2], bhi[2][2];

    // prologue: k-tile 0 full (6 loads), k-tile 1 {A0,B0,A1} (5 loads)
    STAGE_A1(0, 0, 0); STAGE_A1(0, 1, 0); STAGE_B1(0, 0, pB, 0); STAGE_B1(0, 1, pB, 0);
    STAGE_A1(1, 0, 1); STAGE_B1(1, 0, pB, 1); STAGE_A1(1, 1, 1);
    asm volatile("s_waitcnt vmcnt(5)" ::: "memory");
    PH_BARRIER();

#define MFMA_Q1(AF, BF, MO, NO)                                                 \
    _Pragma("unroll") for (int ks = 0; ks < 2; ++ks)                            \
    _Pragma("unroll") for (int mf = 0; mf < 2; ++mf)                            \
    _Pragma("unroll") for (int nf = 0; nf < 2; ++nf)                            \
        acc[(MO) + mf][(NO) + nf] = __builtin_amdgcn_mfma_f32_16x16x32_bf16(    \
            BF[ks][nf], AF[ks][mf], acc[(MO) + mf][(NO) + nf], 0, 0, 0);

    for (int g = 0; g < 4; ++g) {
        const unsigned short* pBn = pB + (size_t)128 * K;
        #pragma unroll
        for (int tt = 0; tt < 8; ++tt) {
            int buf = tt & 1;
            // ---- ph0: alo x blo ; stage B1(gtt+1) ----
            #pragma unroll
            for (int ks = 0; ks < 2; ++ks)
                #pragma unroll
                for (int f = 0; f < 2; ++f) {
                    alo[ks][f] = LD_A1(buf, f, ks);
                    blo[ks][f] = LD_B1(buf, f, ks);
                }
            if (tt < 7) { STAGE_B1(buf ^ 1, 1, pB, tt + 1); }
            else if (g < 3) { STAGE_B1(buf ^ 1, 1, pBn, 0); }
            PH_BARRIER();
            asm volatile("s_waitcnt lgkmcnt(0)" ::: "memory");
            __builtin_amdgcn_sched_barrier(0);
            __builtin_amdgcn_s_setprio(1);
            MFMA_Q1(alo, blo, 0, 0)
            __builtin_amdgcn_s_setprio(0);
            PH_BARRIER();
            // ---- ph1: alo x bhi ; stage A0(gtt+2) ----
            #pragma unroll
            for (int ks = 0; ks < 2; ++ks)
                #pragma unroll
                for (int f = 0; f < 2; ++f) bhi[ks][f] = LD_B1(buf, f + 2, ks);
            if (tt < 6) { STAGE_A1(buf, 0, tt + 2); }
            else if (g < 3) { STAGE_A1(buf, 0, tt - 6); }
            PH_BARRIER();
            asm volatile("s_waitcnt lgkmcnt(0)" ::: "memory");
            __builtin_amdgcn_sched_barrier(0);
            __builtin_amdgcn_s_setprio(1);
            MFMA_Q1(alo, bhi, 0, 2)
            __builtin_amdgcn_s_setprio(0);
            PH_BARRIER();
            // ---- ph2: ahi x bhi ; stage B0(gtt+2) ----
            #pragma unroll
            for (int ks = 0; ks < 2; ++ks)
                #pragma unroll
                for (int f = 0; f < 2; ++f) ahi[ks][f] = LD_A1(buf, f + 2, ks);
            if (tt < 6) { STAGE_B1(buf, 0, pB, tt + 2); }
            else if (g < 3) { STAGE_B1(buf, 0, pBn, tt - 6); }
            PH_BARRIER();
            asm volatile("s_waitcnt lgkmcnt(0)" ::: "memory");
            __builtin_amdgcn_sched_barrier(0);
            __builtin_amdgcn_s_setprio(1);
            MFMA_Q1(ahi, bhi, 2, 2)
            __builtin_amdgcn_s_setprio(0);
            PH_BARRIER();
            // ---- ph3: ahi x blo ; stage A1(gtt+2) ; vmcnt ----
            if (tt < 6) { STAGE_A1(buf, 1, tt + 2); }
            else if (g < 3) { STAGE_A1(buf, 1, tt - 6); }
            PH_BARRIER();
            __builtin_amdgcn_s_setprio(1);
            MFMA_Q1(ahi, blo, 2, 0)
            __builtin_amdgcn_s_setprio(0);
            if (tt < 6) {
                asm volatile("s_waitcnt vmcnt(5)" ::: "memory");
            } else if (tt == 6) {
                if (g < 3) { asm volatile("s_waitcnt vmcnt(5)" ::: "memory"); }
                else       { asm volatile("s_waitcnt vmcnt(0)" ::: "memory"); }
            } else {
                if (g < 3) { asm volatile("s_waitcnt vmcnt(5)" ::: "memory"); }
            }
            PH_BARRIER();
        }
        // ---- per-tile epilogue (no LDS access; overlaps in-flight loads) ----
        {
            unsigned short* Eb = E + (size_t)bz * DKDIM * DKDIM;
            int colbase = bxg * 512 + g * 128;
            int nbase = colbase + wn * 64 + lg * 4;
            float csum[16];
            #pragma unroll
            for (int x = 0; x < 16; ++x) csum[x] = 0.f;
            #pragma unroll
            for (int mf = 0; mf < 4; ++mf) {
                int row = by * 256 + wm * 64 + mf * 16 + lm;
                #pragma unroll
                for (int nf = 0; nf < 4; ++nf) {
                    f32x4 a = acc[mf][nf];
                    float e0 = __expf(scale * a[0]);
                    float e1 = __expf(scale * a[1]);
                    float e2 = __expf(scale * a[2]);
                    float e3 = __expf(scale * a[3]);
                    csum[nf * 4 + 0] += e0;
                    csum[nf * 4 + 1] += e1;
                    csum[nf * 4 + 2] += e2;
                    csum[nf * 4 + 3] += e3;
                    ushort4 o;
                    o.x = f2bf(e0); o.y = f2bf(e1); o.z = f2bf(e2); o.w = f2bf(e3);
                    *reinterpret_cast<ushort4*>(&Eb[(size_t)row * N + nbase + nf * 16]) = o;
                }
            }
            #pragma unroll
            for (int x = 0; x < 16; ++x) {
                float s = csum[x];
                s += __shfl_xor(s, 1, 64);
                s += __shfl_xor(s, 2, 64);
                s += __shfl_xor(s, 4, 64);
                s += __shfl_xor(s, 8, 64);
                csum[x] = s;
            }
            float val = 0.f;
            #pragma unroll
            for (int x = 0; x < 16; ++x)
                if (lm == x) val = csum[x];
            int e = colbase + wn * 64 + (lm >> 2) * 16 + lg * 4 + (lm & 3);
            rpart[((size_t)(by * 4 + wm) * BS + bz) * (size_t)DKDIM + e] = val;
            #pragma unroll
            for (int mf = 0; mf < 4; ++mf)
                #pragma unroll
                for (int nf = 0; nf < 4; ++nf)
                    acc[mf][nf] = f32x4{0.f, 0.f, 0.f, 0.f};
        }
        pB = pBn;
    }
#undef MFMA_Q1
#undef LD_A1
#undef LD_B1
#undef STAGE_A1
#undef STAGE_B1
}

// ---------------------------------------------------------------------------
// GEMM2: out = vp * E^T. BM=256 x BN=128, BK=64, NT=32, 8 waves (4Mx2N),
// 4 quadrant phases of 8 MFMA, counted vmcnt(5). r5-verified INCLUDING the
// XCD-swizzled 1D grid (r7 dropped it: cost ~8µs — restored).
// ---------------------------------------------------------------------------
__global__ __launch_bounds__(512, 2) void gemm2_av_pipe(
    const unsigned short* __restrict__ A,   // vp [b][512][2048]
    const unsigned short* __restrict__ B,   // E  [b][2048][2048]
    float* __restrict__ C)                  // out [b][512][2048]
{
    constexpr int K = DKDIM;    // 2048
    constexpr int N = DKDIM;
    constexpr int NT = K / 64;  // 32

    int wg = blockIdx.x;                    // 0..255
    int swz = (wg & 7) * 32 + (wg >> 3);    // bijective, 256 = 8*32
    int bz = swz >> 5, rem = swz & 31, by = rem >> 4, bx = rem & 15;

    const unsigned short* Ab = A + ((size_t)bz * SEQ + by * 256) * K;
    const unsigned short* Bb = B + ((size_t)bz * DKDIM + bx * 128) * K;

    __shared__ unsigned short lds[2][256 * 64 + 128 * 64];   // A then B

    int t = threadIdx.x;
    int w = t >> 6, l = t & 63;
    int wm = w >> 1, wn = w & 1;     // 4M x 2N
    int lm = l & 15, lg = l >> 4;

    int srow = t >> 3;
    int schunk = (t & 7) ^ (srow & 7);

    int rA = (srow & 31) + ((t >> 8) << 6);
    const unsigned short* pA = Ab + (size_t)rA * K + schunk * 8;
    const unsigned short* pB = Bb + (size_t)rA * K + schunk * 8;

    int aoff[4][2], boff[4][2];
    #pragma unroll
    for (int mf = 0; mf < 4; ++mf)
        #pragma unroll
        for (int ks = 0; ks < 2; ++ks) {
            int arow = wm * 64 + mf * 16 + lm;
            int kc = ks * 4 + lg;
            aoff[mf][ks] = (arow * 64 + ((kc ^ (arow & 7)) << 3)) * 2;
            int brow = wn * 64 + mf * 16 + lm;
            boff[mf][ks] = (16384 + brow * 64 + ((kc ^ (brow & 7)) << 3)) * 2;
        }

#define LD_A2(buf, mf, ks) \
    (*reinterpret_cast<const bf16x8*>((const char*)(&lds[buf][0]) + aoff[mf][ks]))
#define LD_B2(buf, nf, ks) \
    (*reinterpret_cast<const bf16x8*>((const char*)(&lds[buf][0]) + boff[nf][ks]))
#define STAGE_A2(buf, hi, tt) do {                                             \
        const unsigned short* g = pA + (hi) * 32 * K + (tt) * 64;              \
        unsigned short* d = &lds[buf][(hi) * 2048 + ((t >> 8) << 12) + (t & 255) * 8]; \
        gload_lds16(g, d);                                                     \
        gload_lds16(g + (size_t)128 * K, d + 8192);                            \
    } while (0)
#define STAGE_B2(buf, hi, tt) do {                                             \
        const unsigned short* g = pB + (hi) * 32 * K + (tt) * 64;              \
        unsigned short* d = &lds[buf][16384 + (hi) * 2048 + ((t >> 8) << 12) + (t & 255) * 8]; \
        gload_lds16(g, d);                                                     \
    } while (0)

    f32x4 acc[4][4] = {};
    bf16x8 alo[2][2], ahi[2][2], blo[2][2], bhi[2][2];

    STAGE_A2(0, 0, 0); STAGE_A2(0, 1, 0); STAGE_B2(0, 0, 0); STAGE_B2(0, 1, 0);
    STAGE_A2(1, 0, 1); STAGE_B2(1, 0, 1); STAGE_A2(1, 1, 1);
    asm volatile("s_waitcnt vmcnt(5)" ::: "memory");
    PH_BARRIER();

#define MFMA_Q2(AF, BF, MO, NO)                                                 \
    _Pragma("unroll") for (int ks = 0; ks < 2; ++ks)                            \
    _Pragma("unroll") for (int mf = 0; mf < 2; ++mf)                            \
    _Pragma("unroll") for (int nf = 0; nf < 2; ++nf)                            \
        acc[(MO) + mf][(NO) + nf] = __builtin_amdgcn_mfma_f32_16x16x32_bf16(    \
            BF[ks][nf], AF[ks][mf], acc[(MO) + mf][(NO) + nf], 0, 0, 0);

    #pragma unroll 2
    for (int tt = 0; tt < NT; ++tt) {
        int buf = tt & 1;
        // ---- ph0: alo x blo ----
        #pragma unroll
        for (int ks = 0; ks < 2; ++ks)
            #pragma unroll
            for (int f = 0; f < 2; ++f) {
                alo[ks][f] = LD_A2(buf, f, ks);
                blo[ks][f] = LD_B2(buf, f, ks);
            }
        if (tt + 1 < NT) STAGE_B2(buf ^ 1, 1, tt + 1);
        PH_BARRIER();
        asm volatile("s_waitcnt lgkmcnt(0)" ::: "memory");
        __builtin_amdgcn_sched_barrier(0);
        __builtin_amdgcn_s_setprio(1);
        MFMA_Q2(alo, blo, 0, 0)
        __builtin_amdgcn_s_setprio(0);
        PH_BARRIER();
        // ---- ph1: alo x bhi ----
        #pragma unroll
        for (int ks = 0; ks < 2; ++ks)
            #pragma unroll
            for (int f = 0; f < 2; ++f) bhi[ks][f] = LD_B2(buf, f + 2, ks);
        if (tt + 2 < NT) STAGE_A2(buf, 0, tt + 2);
        PH_BARRIER();
        asm volatile("s_waitcnt lgkmcnt(0)" ::: "memory");
        __builtin_amdgcn_sched_barrier(0);
        __builtin_amdgcn_s_setprio(1);
        MFMA_Q2(alo, bhi, 0, 2)
        __builtin_amdgcn_s_setprio(0);
        PH_BARRIER();
        // ---- ph2: ahi x bhi ----
        #pragma unroll
        for (int ks = 0; ks < 2; ++ks)
            #pragma unroll
            for (int f = 0; f < 2; ++f) ahi[ks][f] = LD_A2(buf, f + 2, ks);
        if (tt + 2 < NT) STAGE_B2(buf, 0, tt + 2);
        PH_BARRIER();
        asm volatile("s_waitcnt lgkmcnt(0)" ::: "memory");
        __builtin_amdgcn_sched_barrier(0);
        __builtin_amdgcn_s_setprio(1);
        MFMA_Q2(ahi, bhi, 2, 2)
        __builtin_amdgcn_s_setprio(0);
        PH_BARRIER();
        // ---- ph3: ahi x blo (regs held) ----
        if (tt + 2 < NT) STAGE_A2(buf, 1, tt + 2);
        PH_BARRIER();
        __builtin_amdgcn_s_setprio(1);
        MFMA_Q2(ahi, blo, 2, 0)
        __builtin_amdgcn_s_setprio(0);
        if (tt < NT - 2) {
            asm volatile("s_waitcnt vmcnt(5)" ::: "memory");
        } else if (tt == NT - 2) {
            asm volatile("s_waitcnt vmcnt(0)" ::: "memory");
        }
        PH_BARRIER();
    }
#undef MFMA_Q2
#undef LD_A2
#undef LD_B2
#undef STAGE_A2
#undef STAGE_B2

    float* Cf = C + (size_t)bz * SEQ * DKDIM;
    int mbase = by * 256 + wm * 64 + lm;
    int nbase = bx * 128 + wn * 64 + lg * 4;
    #pragma unroll
    for (int i = 0; i < 4; ++i)
        #pragma unroll
        for (int j = 0; j < 4; ++j)
            *reinterpret_cast<f32x4*>(&Cf[(size_t)(mbase + i * 16) * N + nbase + j * 16]) = acc[i][j];
}

// ---------------------------------------------------------------------------
// rinv[b][e] = 1 / sum over 32 partials
// ---------------------------------------------------------------------------
__global__ __launch_bounds__(256) void colsum_finish(
    const float* __restrict__ rpart, float* __restrict__ rinv)
{
    int i = blockIdx.x * 256 + threadIdx.x;
    float s = 0.f;
    #pragma unroll
    for (int p = 0; p < 32; ++p) s += rpart[(size_t)p * BS * DKDIM + i];
    rinv[i] = 1.0f / s;
}

// ---------------------------------------------------------------------------
// v'[b][s][e] = bf16( v[b][s][e] * rinv[b][e] )
// ---------------------------------------------------------------------------
__global__ __launch_bounds__(256) void vprime_kernel(
    const float* __restrict__ v, const float* __restrict__ rinv,
    unsigned short* __restrict__ vp)
{
    size_t i4 = ((size_t)blockIdx.x * 256 + threadIdx.x) * 4;
    int e = (int)(i4 & (DKDIM - 1));
    int b = (int)(i4 >> 20);
    float4 v4 = *reinterpret_cast<const float4*>(&v[i4]);
    float4 r4 = *reinterpret_cast<const float4*>(&rinv[(size_t)b * DKDIM + e]);
    ushort4 o;
    o.x = f2bf(v4.x * r4.x);
    o.y = f2bf(v4.y * r4.y);
    o.z = f2bf(v4.z * r4.z);
    o.w = f2bf(v4.w * r4.w);
    *reinterpret_cast<ushort4*>(&vp[i4]) = o;
}

extern "C" void kernel_launch(void* const* d_in, const int* in_sizes, int n_in,
                              void* d_out, int out_size, void* d_ws, size_t ws_size,
                              hipStream_t stream) {
    const float* q = (const float*)d_in[0];
    const float* k = (const float*)d_in[1];
    const float* v = (const float*)d_in[2];
    float* out = (float*)d_out;

    char* ws = (char*)d_ws;
    unsigned short* qT = (unsigned short*)(ws);                        // 16 MB
    unsigned short* kT = (unsigned short*)(ws + 16777216);             // 16 MB
    unsigned short* E  = (unsigned short*)(ws + 33554432);             // 64 MB
    float* rpart       = (float*)(ws + 100663296);                     // 2 MB (32x8x2048 f32)
    float* rinv        = (float*)(ws + 102760448);                     // 64 KB
    unsigned short* vp = (unsigned short*)(ws + 103809024);            // 16 MB

    const float scale = 0.022097086912079608f;  // 1/sqrt(2048)

    transpose_conv_kernel<<<dim3(DKDIM / 64, SEQ / 64, 2 * BS), 256, 0, stream>>>(q, k, qT, kT);

    gemm1_qk_exp<<<dim3(256), 512, 0, stream>>>(qT, kT, E, rpart, scale);

    colsum_finish<<<dim3(BS * DKDIM / 256), 256, 0, stream>>>(rpart, rinv);

    vprime_kernel<<<dim3(BS * SEQ * DKDIM / 1024), 256, 0, stream>>>(v, rinv, vp);

    gemm2_av_pipe<<<dim3(256), 512, 0, stream>>>(vp, E, out);
}